// Round 7
// baseline (510.995 us; speedup 1.0000x reference)
//
#include <hip/hip_runtime.h>
#include <hip/hip_bf16.h>
#include <stdint.h>

typedef int v4i __attribute__((ext_vector_type(4)));
typedef int v16i __attribute__((ext_vector_type(16)));

#define GM 4096
#define GN 16384
#define GK 4096
#define BM 256
#define BN 256
#define BK 128            // i8 bytes per K-step
#define NTILES (GK / BK)  // 32

__device__ __forceinline__ void gload16(const void* g, void* l) {
  __builtin_amdgcn_global_load_lds(
      (const __attribute__((address_space(1))) void*)g,
      (__attribute__((address_space(3))) void*)l, 16, 0, 0);
}

// ---------------- per-row dynamic quantization (x f32 -> int8 + scale) ----------------
__global__ __launch_bounds__(256) void quant_rows(
    const float* __restrict__ x, int8_t* __restrict__ xq,
    float* __restrict__ xs, int K) {
  const int row = blockIdx.x;
  const int t = threadIdx.x;
  const float4* src = (const float4*)(x + (size_t)row * K) + t * 4;
  float4 v[4];
  float m = 0.f;
#pragma unroll
  for (int i = 0; i < 4; ++i) {
    v[i] = src[i];
    m = fmaxf(m, fmaxf(fmaxf(fabsf(v[i].x), fabsf(v[i].y)),
                       fmaxf(fabsf(v[i].z), fabsf(v[i].w))));
  }
#pragma unroll
  for (int off = 1; off < 64; off <<= 1)
    m = fmaxf(m, __shfl_xor(m, off, 64));
  __shared__ float wmax[4];
  if ((t & 63) == 0) wmax[t >> 6] = m;
  __syncthreads();
  const float gm = fmaxf(fmaxf(wmax[0], wmax[1]), fmaxf(wmax[2], wmax[3]));
  const float scale = (gm + 1e-5f) / 127.0f;  // == ref x_scales
  if (t == 0) xs[row] = scale;
  unsigned packed[4];
#pragma unroll
  for (int i = 0; i < 4; ++i) {
    float fv[4] = {v[i].x, v[i].y, v[i].z, v[i].w};
    unsigned p = 0;
#pragma unroll
    for (int j = 0; j < 4; ++j) {
      int q = (int)rintf(fv[j] / scale);  // RNE, matches np.round
      q = max(-128, min(127, q));
      p |= (unsigned)(q & 0xff) << (8 * j);
    }
    packed[i] = p;
  }
  *(int4*)(xq + (size_t)row * K + t * 16) =
      make_int4((int)packed[0], (int)packed[1], (int)packed[2], (int)packed[3]);
}

// ------- W int32 [K][N] -> Wt2 packed MFMA-fragment order -------
// Wt2[tn][kt][f 0..7][s 0..3][lane 0..63][16B]:
//   lane l holds n = tn*256+f*32+(l&31), k = kt*128+s*32+(l>>5)*16 .. +16
__global__ __launch_bounds__(256) void transpose_pack(
    const int* __restrict__ W32, int8_t* __restrict__ Wt2, int K, int N) {
  __shared__ __align__(16) int8_t tile[64][80];
  const int t = threadIdx.x;
  const int n0 = blockIdx.x * 64;
  const int k0 = blockIdx.y * 64;
  const int ln = t & 63;
  const int wv = t >> 6;
#pragma unroll
  for (int it = 0; it < 16; ++it) {
    const int kk = wv * 16 + it;
    tile[ln][kk] = (int8_t)W32[(size_t)(k0 + kk) * N + n0 + ln];
  }
  __syncthreads();
  const int f2 = wv >> 1, s2 = wv & 1;
  const int4 v = *(const int4*)&tile[f2 * 32 + (ln & 31)][s2 * 32 + (ln >> 5) * 16];
  const int tn = n0 >> 8;
  const int fb = ((n0 & 255) >> 5) + f2;
  const int kt = k0 >> 7;
  const int sb = ((k0 & 127) >> 5) + s2;
  *(int4*)(Wt2 +
           ((((size_t)(tn * 32 + kt) * 8 + fb) * 4 + sb) * 64 + ln) * 16) = v;
}

// -------- int8 GEMM: A via LDS (swizzled), B direct global->VGPR (prepacked) --------
__global__ __launch_bounds__(512, 2) void gemm_i8(
    const int8_t* __restrict__ Xq, const int8_t* __restrict__ Wt2,
    const float* __restrict__ xs, const float* __restrict__ wsc,
    const float* __restrict__ bias, float* __restrict__ C) {
  __shared__ __align__(16) int8_t lA[2][BM][BK];  // 2 x 32 KB only

  const int t = threadIdx.x;
  const int lane = t & 63;
  const int w = t >> 6;
  const int wr = w >> 1;  // 0..3 (M quarter: 64 rows)
  const int wc = w & 1;   // 0..1 (N half: 128 cols)
  const int l31 = lane & 31;
  const int kg2 = lane >> 5;

  // bijective XCD swizzle: 1024 blocks = 8 XCD x (16 M x 8 N) rectangles
  const int bid = blockIdx.x;
  const int xcd = bid & 7;
  const int q = bid >> 3;
  const int tm = q & 15;
  const int tn = xcd * 8 + (q >> 4);
  const size_t rowA0 = (size_t)tm * BM;
  const size_t rowB0 = (size_t)tn * BN;

  // A staging: 2048 16B-slots; slot=(i*8+w)*64+lane; r=slot>>3;
  // stored chunk sc=slot&7 holds logical chunk c=sc^(r&7) (pre-swizzled source).
  const int8_t* XqB = Xq + rowA0 * GK;
  int srcOff[4], dstOff[4];
#pragma unroll
  for (int i = 0; i < 4; ++i) {
    const int slot0 = (i * 8 + w) * 64;
    const int slot = slot0 + lane;
    const int r = slot >> 3;
    const int c = (slot & 7) ^ (r & 7);
    srcOff[i] = r * GK + c * 16;
    dstOff[i] = slot0 * 16;  // wave-uniform LDS base
  }

#define STAGE(KT, D)                                                        \
  _Pragma("unroll") for (int i = 0; i < 4; ++i)                             \
      gload16(XqB + srcOff[i] + (KT)*BK, (int8_t*)&lA[(D)][0][0] + dstOff[i]);

  // A fragment swizzled chunk offsets, slice s
  int ck[4];
#pragma unroll
  for (int s = 0; s < 4; ++s) ck[s] = ((2 * s + kg2) ^ (l31 & 7)) * 16;

  v16i acc[2][4] = {};
  v4i areg[2][4], breg[4][4];

  // B panel base for this wave (prepacked): + f*4096 + s*1024 + lane*16
  const int8_t* bq = Wt2 + (size_t)tn * 1048576 + wc * 16384 + lane * 16;

#define RD_A(MI, D)                                               \
  {                                                               \
    const int8_t* p = &lA[(D)][wr * 64 + (MI)*32 + l31][0];       \
    _Pragma("unroll") for (int s = 0; s < 4; ++s)                 \
        areg[MI][s] = *(const v4i*)(p + ck[s]);                   \
  }
#define LOADB(NJ, KT)                                             \
  _Pragma("unroll") for (int s = 0; s < 4; ++s)                   \
      breg[NJ][s] =                                               \
          *(const v4i*)(bq + (size_t)(KT)*32768 + (NJ)*4096 + s * 1024);

#define MFMA_F(MI, NJ)                                            \
  _Pragma("unroll") for (int s = 0; s < 4; ++s)                   \
      acc[MI][NJ] = __builtin_amdgcn_mfma_i32_32x32x32_i8(        \
          areg[MI][s], breg[NJ][s], acc[MI][NJ], 0, 0, 0);

  // prologue: stage A tile 0
  STAGE(0, 0);

  for (int kt = 0; kt < NTILES; ++kt) {
    const int d = kt & 1;
    // rendezvous: my A-stage of tile kt landed; barrier => CU-wide resident
    // AND all waves' reads of tile kt-1 done (their lgkm(0) gate preceded).
    asm volatile("s_waitcnt vmcnt(0)" ::: "memory");
    __builtin_amdgcn_s_barrier();
    // issue: 16 B loads (nj-major), 4 A-stage gloads, 8 A ds_reads
    LOADB(0, kt);
    LOADB(1, kt);
    __builtin_amdgcn_sched_barrier(0);
    LOADB(2, kt);
    LOADB(3, kt);
    __builtin_amdgcn_sched_barrier(0);
    STAGE((kt + 1) & (NTILES - 1), d ^ 1);  // dummy-stage tile 0 on last iter
    __builtin_amdgcn_sched_barrier(0);
    RD_A(0, d);
    RD_A(1, d);
    __builtin_amdgcn_sched_barrier(0);
    // gate1: first 8 B loads (nj 0,1) + all A reads done; 4 stages + 8 B out
    asm volatile("s_waitcnt vmcnt(12) lgkmcnt(0)" ::: "memory");
    __builtin_amdgcn_sched_barrier(0);
    __builtin_amdgcn_s_setprio(1);
    MFMA_F(0, 0);
    MFMA_F(1, 0);
    MFMA_F(0, 1);
    MFMA_F(1, 1);
    __builtin_amdgcn_s_setprio(0);
    // gate2: all B done (4 stages outstanding)
    asm volatile("s_waitcnt vmcnt(4)" ::: "memory");
    __builtin_amdgcn_sched_barrier(0);
    __builtin_amdgcn_s_setprio(1);
    MFMA_F(0, 2);
    MFMA_F(1, 2);
    MFMA_F(0, 3);
    MFMA_F(1, 3);
    __builtin_amdgcn_s_setprio(0);
  }

  // epilogue: dequant + bias -> bf16-round -> f32 store
  // 32x32 C/D: col = lane&31, row = (reg&3) + 8*(reg>>2) + 4*(lane>>5)
#pragma unroll
  for (int nj = 0; nj < 4; ++nj) {
    const int col_l = wc * 128 + nj * 32 + l31;
    const float wsv = wsc[rowB0 + col_l];
    const float bv = bias[rowB0 + col_l];
#pragma unroll
    for (int mi = 0; mi < 2; ++mi) {
#pragma unroll
      for (int r = 0; r < 16; ++r) {
        const size_t row =
            rowA0 + wr * 64 + mi * 32 + (r & 3) + 8 * (r >> 2) + 4 * kg2;
        const float f = (float)acc[mi][nj][r] * xs[row] * wsv + bv;
        C[row * GN + rowB0 + col_l] = __bfloat162float(__float2bfloat16(f));
      }
    }
  }
}

extern "C" void kernel_launch(void* const* d_in, const int* in_sizes, int n_in,
                              void* d_out, int out_size, void* d_ws, size_t ws_size,
                              hipStream_t stream) {
  const int M = GM, K = GK, N = GN;
  const float* x = (const float*)d_in[0];
  const int* W32 = (const int*)d_in[1];  // harness pushes integer inputs as int32
  const float* wsc = (const float*)d_in[2];
  const float* bias = (const float*)d_in[3];
  float* out = (float*)d_out;  // reference output dtype is float32 (bf16-rounded)

  // workspace layout: xs (16KB) | Xq (16MB) | Wt2 (64MB packed)
  float* xs = (float*)d_ws;
  int8_t* Xq = (int8_t*)d_ws + 16384;
  int8_t* Wt2 = (int8_t*)d_ws + 16384 + (size_t)M * K;

  transpose_pack<<<dim3(N / 64, K / 64), 256, 0, stream>>>(W32, Wt2, K, N);
  quant_rows<<<M, 256, 0, stream>>>(x, Xq, xs, K);
  gemm_i8<<<dim3((M / BM) * (N / BN)), 512, 0, stream>>>(Xq, Wt2, xs, wsc, bias,
                                                         out);
}